// Round 1
// baseline (3700.190 us; speedup 1.0000x reference)
//
#include <hip/hip_runtime.h>
#include <stdint.h>

// ---------------- problem constants ----------------
#define NU 50000
#define NI 30000
#define NN 80000   // NU+NI
#define EK 64
#define HK 32
#define KV 4096
#define KT 384
#define NNZ_A 2000000
#define NNZ_R 1000000

// JAX >= 0.4.36 defaults jax_threefry_partitionable=True. Flip to 0 if the
// bench shows large error concentrated on the gumbel-dependent outputs.
#define JAX_PARTITIONABLE 1

// ---------------- threefry2x32 (20 rounds) ----------------
__host__ __device__ static inline void tf2x32(uint32_t k0, uint32_t k1,
                                              uint32_t x0, uint32_t x1,
                                              uint32_t& o0, uint32_t& o1) {
  uint32_t ks2 = k0 ^ k1 ^ 0x1BD11BDAu;
#define ROTL(x,d) (((x)<<(d))|((x)>>(32-(d))))
#define RND(r) { x0 += x1; x1 = ROTL(x1,r); x1 ^= x0; }
  x0 += k0; x1 += k1;
  RND(13) RND(15) RND(26) RND(6)
  x0 += k1;  x1 += ks2 + 1u;
  RND(17) RND(29) RND(16) RND(24)
  x0 += ks2; x1 += k0 + 2u;
  RND(13) RND(15) RND(26) RND(6)
  x0 += k0;  x1 += k1 + 3u;
  RND(17) RND(29) RND(16) RND(24)
  x0 += k1;  x1 += ks2 + 4u;
  RND(13) RND(15) RND(26) RND(6)
  x0 += ks2; x1 += k0 + 5u;
  o0 = x0; o1 = x1;
#undef RND
#undef ROTL
}

// ---------------- CSR build ----------------
__global__ void k_hist(const int* __restrict__ rows, int n, int* __restrict__ cnt) {
  int g = blockIdx.x * blockDim.x + threadIdx.x;
  if (g < n) atomicAdd(&cnt[rows[g]], 1);
}

// single-block exclusive scan (1024 threads), writes ptr[0..n] and fill[0..n-1]=ptr
__global__ void k_exscan(const int* __restrict__ cnt, int* __restrict__ ptr,
                         int* __restrict__ fill, int n) {
  __shared__ int wsum[16];
  __shared__ int s_carry;
  int tid = threadIdx.x;
  int lane = tid & 63, w = tid >> 6;
  if (tid == 0) s_carry = 0;
  __syncthreads();
  for (int base = 0; base < n; base += 1024) {
    int i = base + tid;
    int v = (i < n) ? cnt[i] : 0;
    int x = v;
    #pragma unroll
    for (int off = 1; off < 64; off <<= 1) {
      int y = __shfl_up(x, off, 64);
      if (lane >= off) x += y;
    }
    if (lane == 63) wsum[w] = x;
    __syncthreads();
    if (w == 0 && lane < 16) {
      int t = wsum[lane];
      #pragma unroll
      for (int off = 1; off < 16; off <<= 1) {
        int y = __shfl_up(t, off, 64);
        if (lane >= off) t += y;
      }
      wsum[lane] = t; // inclusive over wave sums
    }
    __syncthreads();
    int waveoff = (w == 0) ? 0 : wsum[w - 1];
    int excl = s_carry + waveoff + x - v;
    if (i < n) { ptr[i] = excl; fill[i] = excl; }
    __syncthreads();
    if (tid == 0) s_carry += wsum[15];
    __syncthreads();
  }
  if (tid == 0) ptr[n] = s_carry;
}

__global__ void k_scatter(const int* __restrict__ rows, const int* __restrict__ cols,
                          const float* __restrict__ vals, int n,
                          int* __restrict__ fill, int* __restrict__ ccol,
                          float* __restrict__ cval) {
  int g = blockIdx.x * blockDim.x + threadIdx.x;
  if (g >= n) return;
  int p = atomicAdd(&fill[rows[g]], 1);
  ccol[p] = cols[g];
  cval[p] = vals[g];
}

// ---------------- dense GEMM: C(M x 96) = A(M x K) @ B(K x 96) ----------------
// cols 0..31 -> outIH (M x 32), cols 32..95 -> outIF (M x 64)
#define BM 128
#define BK 32
__global__ __launch_bounds__(256) void k_gemm96(const float* __restrict__ A,
                                                const float* __restrict__ B,
                                                float* __restrict__ outIH,
                                                float* __restrict__ outIF,
                                                int M, int K) {
  __shared__ float As[BM][BK + 1];
  __shared__ float Bs[BK][96];
  int tid = threadIdx.x;
  int tx = tid & 15, ty = tid >> 4;       // 16 x 16
  int row0 = blockIdx.x * BM;
  float acc[8][6] = {};
  for (int k0 = 0; k0 < K; k0 += BK) {
    #pragma unroll
    for (int l = 0; l < 16; ++l) {        // 128*32/256
      int idx = l * 256 + tid;
      int r = idx >> 5, kk = idx & 31;
      int gr = row0 + r;
      As[r][kk] = (gr < M) ? A[(size_t)gr * K + k0 + kk] : 0.0f;
    }
    #pragma unroll
    for (int l = 0; l < 12; ++l) {        // 32*96/256
      int idx = l * 256 + tid;
      int kk = idx / 96, c = idx % 96;
      Bs[kk][c] = B[(size_t)(k0 + kk) * 96 + c];
    }
    __syncthreads();
    #pragma unroll
    for (int kk = 0; kk < BK; ++kk) {
      float a[8], b[6];
      #pragma unroll
      for (int i = 0; i < 8; ++i) a[i] = As[ty * 8 + i][kk];
      #pragma unroll
      for (int j = 0; j < 6; ++j) b[j] = Bs[kk][tx * 6 + j];
      #pragma unroll
      for (int i = 0; i < 8; ++i)
        #pragma unroll
        for (int j = 0; j < 6; ++j) acc[i][j] += a[i] * b[j];
    }
    __syncthreads();
  }
  for (int i = 0; i < 8; ++i) {
    int gr = row0 + ty * 8 + i;
    if (gr >= M) continue;
    for (int j = 0; j < 6; ++j) {
      int c = tx * 6 + j;
      float v = acc[i][j];
      if (c < 32) outIH[(size_t)gr * 32 + c] = v;
      else        outIF[(size_t)gr * 64 + (c - 32)] = v;
    }
  }
}

// ---------------- CSR SpMM ----------------
__global__ void k_spmm32(const int* __restrict__ ptr, const int* __restrict__ col,
                         const float* __restrict__ val, const float* __restrict__ x,
                         float* __restrict__ y, int nrows) {
  int g = blockIdx.x * blockDim.x + threadIdx.x;
  int row = g >> 5, lane = g & 31;
  if (row >= nrows) return;
  int jb = ptr[row], je = ptr[row + 1];
  float acc = 0.0f;
  for (int j = jb; j < je; ++j) acc += val[j] * x[(size_t)col[j] * 32 + lane];
  y[(size_t)row * 32 + lane] = acc;
}

__global__ void k_spmm64(const int* __restrict__ ptr, const int* __restrict__ col,
                         const float* __restrict__ val, const float* __restrict__ x,
                         float* __restrict__ y, int nrows,
                         const float* __restrict__ rowscale) {
  int g = blockIdx.x * blockDim.x + threadIdx.x;
  int row = g >> 6, lane = g & 63;
  if (row >= nrows) return;
  int jb = ptr[row], je = ptr[row + 1];
  float acc = 0.0f;
  for (int j = jb; j < je; ++j) acc += val[j] * x[(size_t)col[j] * 64 + lane];
  if (rowscale) acc *= rowscale[row];
  y[(size_t)row * 64 + lane] = acc;
}

// ---------------- gumbel softmax (in-place over n x 32) ----------------
__global__ void k_gumbel_softmax(float* __restrict__ logits, int nrows,
                                 uint32_t k0, uint32_t k1) {
  int row = blockIdx.x * 8 + (threadIdx.x >> 5);
  int c = threadIdx.x & 31;
  if (row >= nrows) return;
  int e = row * 32 + c;
  uint32_t b0, b1, bits;
#if JAX_PARTITIONABLE
  tf2x32(k0, k1, 0u, (uint32_t)e, b0, b1);
  bits = b0 ^ b1;
#else
  int half = nrows * 16;
  if (e < half) { tf2x32(k0, k1, (uint32_t)e, (uint32_t)(e + half), b0, b1); bits = b0; }
  else          { tf2x32(k0, k1, (uint32_t)(e - half), (uint32_t)e, b0, b1); bits = b1; }
#endif
  const float TINY = 1.1754943508222875e-38f;
  float f = __uint_as_float((bits >> 9) | 0x3F800000u) - 1.0f;  // [0,1)
  float u = fmaxf(TINY, f + TINY);
  float g = -logf(-logf(u));
  float x = (logits[e] + g) / 0.2f;
  float m = x;
  #pragma unroll
  for (int off = 16; off; off >>= 1) m = fmaxf(m, __shfl_xor(m, off, 32));
  float ex = expf(x - m);
  float s = ex;
  #pragma unroll
  for (int off = 16; off; off >>= 1) s += __shfl_xor(s, off, 32);
  logits[e] = ex / s;
}

// ---------------- small utility kernels ----------------
__global__ void k_copy(const float* __restrict__ s, float* __restrict__ d, int n) {
  int g = blockIdx.x * blockDim.x + threadIdx.x;
  if (g < n) d[g] = s[g];
}

__global__ void k_cge(const float* __restrict__ e0, const float* __restrict__ e1,
                      const float* __restrict__ e2, float* __restrict__ cge, int n) {
  int g = blockIdx.x * blockDim.x + threadIdx.x;
  if (g < n) cge[g] = (e0[g] + e1[g] + e2[g]) / 3.0f;
}

__global__ void k_l2norm_add(const float* __restrict__ x, float* __restrict__ msum,
                             int nrows) {
  int g = blockIdx.x * blockDim.x + threadIdx.x;
  int row = g >> 6, lane = g & 63;
  if (row >= nrows) return;
  size_t idx = (size_t)row * 64 + lane;
  float v = x[idx];
  float s = v * v;
  #pragma unroll
  for (int off = 32; off; off >>= 1) s += __shfl_xor(s, off, 64);
  float inv = 1.0f / fmaxf(sqrtf(s), 1e-12f);
  msum[idx] += v * inv;
}

// lat(32x64) += H(n x 32)^T @ X(n x 64)
__global__ void k_lat(const float* __restrict__ H, const float* __restrict__ X,
                      float* __restrict__ lat, int n) {
  int tid = threadIdx.x;
  int a = tid & 31, w = tid >> 5;        // w in 0..7 -> 8 cols each
  int i0 = blockIdx.x * 128;
  int iend = min(i0 + 128, n);
  float acc[8] = {};
  for (int i = i0; i < iend; ++i) {
    float h = H[(size_t)i * 32 + a];
    const float* xr = X + (size_t)i * 64 + w * 8;
    #pragma unroll
    for (int j = 0; j < 8; ++j) acc[j] += h * xr[j];
  }
  #pragma unroll
  for (int j = 0; j < 8; ++j) atomicAdd(&lat[a * 64 + w * 8 + j], acc[j]);
}

// out(n x 64) = H(n x 32) @ lat(32 x 64)
__global__ void k_hyper_out(const float* __restrict__ H, const float* __restrict__ lat,
                            float* __restrict__ out, int n) {
  __shared__ float ls[2048];
  int tid = threadIdx.x;
  for (int l = tid; l < 2048; l += 256) ls[l] = lat[l];
  __syncthreads();
  int row = blockIdx.x * 4 + (tid >> 6);
  int lane = tid & 63;
  if (row >= n) return;
  const float* h = H + (size_t)row * 32;
  float acc = 0.0f;
  #pragma unroll
  for (int a = 0; a < 32; ++a) acc += h[a] * ls[a * 64 + lane];
  out[(size_t)row * 64 + lane] = acc;
}

// B concat: bcat(K x 96) = [hyp(K x 32) | trs(K x 64)]
__global__ void k_concat_b(const float* __restrict__ hyp, const float* __restrict__ trs,
                           float* __restrict__ b, int K) {
  int g = blockIdx.x * blockDim.x + threadIdx.x;
  if (g >= K * 96) return;
  int k = g / 96, c = g % 96;
  b[g] = (c < 32) ? hyp[(size_t)k * 32 + c] : trs[(size_t)k * 64 + (c - 32)];
}

// final: lge = cge+msum; ghe from hyper outs; out = lge + 0.2*l2norm(ghe)
__global__ void k_final(const float* __restrict__ cge, const float* __restrict__ msum,
                        const float* __restrict__ o2, const float* __restrict__ o3,
                        const float* __restrict__ o4, const float* __restrict__ o5,
                        float* __restrict__ o0, float* __restrict__ o1) {
  int g = blockIdx.x * blockDim.x + threadIdx.x;
  int row = g >> 6, lane = g & 63;
  if (row >= NN) return;
  size_t idx = (size_t)row * 64 + lane;
  float lge = cge[idx] + msum[idx];
  float gv;
  size_t sub;
  if (row < NU) { sub = (size_t)row * 64 + lane;        gv = o2[sub] + o4[sub]; }
  else          { sub = (size_t)(row - NU) * 64 + lane; gv = o3[sub] + o5[sub]; }
  float s = gv * gv;
  #pragma unroll
  for (int off = 32; off; off >>= 1) s += __shfl_xor(s, off, 64);
  float inv = 1.0f / fmaxf(sqrtf(s), 1e-12f);
  float res = lge + 0.2f * gv * inv;
  if (row < NU) o0[sub] = res;
  else          o1[sub] = res;
}

static inline int cdiv(int a, int b) { return (a + b - 1) / b; }

extern "C" void kernel_launch(void* const* d_in, const int* in_sizes, int n_in,
                              void* d_out, int out_size, void* d_ws, size_t ws_size,
                              hipStream_t stream) {
  const float* Gu        = (const float*)d_in[0];
  const float* Gi        = (const float*)d_in[1];
  const float* feat_v    = (const float*)d_in[2];
  const float* feat_t    = (const float*)d_in[3];
  const float* trs_v     = (const float*)d_in[4];
  const float* trs_t     = (const float*)d_in[5];
  const float* hyp_v     = (const float*)d_in[6];
  const float* hyp_t     = (const float*)d_in[7];
  const float* inv_inters= (const float*)d_in[8];
  const float* adj_vals  = (const float*)d_in[9];
  const float* r_vals    = (const float*)d_in[10];
  const int*   adj_rows  = (const int*)d_in[11];
  const int*   adj_cols  = (const int*)d_in[12];
  const int*   r_rows    = (const int*)d_in[13];
  const int*   r_cols    = (const int*)d_in[14];

  float* W = (float*)d_ws;
  size_t off = 0;
  auto alloc = [&](size_t n) { float* p = W + off; off += (n + 63) & ~(size_t)63; return p; };
  int*   cntA  = (int*)alloc(NN);
  int*   ptrA  = (int*)alloc(NN + 1);
  int*   fillA = (int*)alloc(NN);
  int*   colA  = (int*)alloc(NNZ_A);
  float* valA  = alloc(NNZ_A);
  int*   cntR  = (int*)alloc(NU);
  int*   ptrR  = (int*)alloc(NU + 1);
  int*   fillR = (int*)alloc(NU);
  int*   colR  = (int*)alloc(NNZ_R);
  float* valR  = alloc(NNZ_R);
  float* bcv   = alloc((size_t)KV * 96);
  float* bct   = alloc((size_t)KT * 96);
  float* ihv   = alloc((size_t)NI * 32);
  float* iht   = alloc((size_t)NI * 32);
  float* itfv  = alloc((size_t)NI * 64);
  float* itft  = alloc((size_t)NI * 64);
  float* uhv   = alloc((size_t)NU * 32);
  float* uht   = alloc((size_t)NU * 32);
  float* ego   = alloc((size_t)NN * 64);   // later reused as mge0
  float* t1b   = alloc((size_t)NN * 64);   // later reused as mge1
  float* t2b   = alloc((size_t)NN * 64);
  float* cgeb  = alloc((size_t)NN * 64);
  float* msum  = alloc((size_t)NN * 64);
  float* latv  = alloc(2048);
  float* latt  = alloc(2048);
  (void)ws_size; (void)in_sizes; (void)n_in; (void)out_size;

  float* o0 = (float*)d_out;
  float* o1 = o0 + (size_t)NU * 64;
  float* o2 = o1 + (size_t)NI * 64;
  float* o3 = o2 + (size_t)NU * 64;
  float* o4 = o3 + (size_t)NI * 64;
  float* o5 = o4 + (size_t)NU * 64;

  // ---- PRNG key derivation on host: key(42) -> fold_in(m) -> split ----
  uint32_t ks[2][4];
  for (int m = 0; m < 2; ++m) {
    uint32_t a, b;
    tf2x32(0u, 42u, 0u, (uint32_t)m, a, b);
#if JAX_PARTITIONABLE
    uint32_t p0, p1, q0, q1;
    tf2x32(a, b, 0u, 0u, p0, p1);   // k1
    tf2x32(a, b, 0u, 1u, q0, q1);   // k2
    ks[m][0] = p0; ks[m][1] = p1; ks[m][2] = q0; ks[m][3] = q1;
#else
    uint32_t p0, p1, q0, q1;
    tf2x32(a, b, 0u, 2u, p0, p1);
    tf2x32(a, b, 1u, 3u, q0, q1);
    ks[m][0] = p0; ks[m][1] = q0; ks[m][2] = p1; ks[m][3] = q1;
#endif
  }

  // ---- zero init ----
  hipMemsetAsync(cntA, 0, (size_t)NN * 4, stream);
  hipMemsetAsync(cntR, 0, (size_t)NU * 4, stream);
  hipMemsetAsync(latv, 0, 2048 * 4, stream);
  hipMemsetAsync(latt, 0, 2048 * 4, stream);
  hipMemsetAsync(msum, 0, (size_t)NN * 64 * 4, stream);

  // ---- CSR build for adj and R ----
  k_hist<<<cdiv(NNZ_A, 256), 256, 0, stream>>>(adj_rows, NNZ_A, cntA);
  k_hist<<<cdiv(NNZ_R, 256), 256, 0, stream>>>(r_rows, NNZ_R, cntR);
  k_exscan<<<1, 1024, 0, stream>>>(cntA, ptrA, fillA, NN);
  k_exscan<<<1, 1024, 0, stream>>>(cntR, ptrR, fillR, NU);
  k_scatter<<<cdiv(NNZ_A, 256), 256, 0, stream>>>(adj_rows, adj_cols, adj_vals, NNZ_A, fillA, colA, valA);
  k_scatter<<<cdiv(NNZ_R, 256), 256, 0, stream>>>(r_rows, r_cols, r_vals, NNZ_R, fillR, colR, valR);

  // ---- dense GEMMs: [ih_logits | item_feats] = feat @ [hyp | trs] ----
  k_concat_b<<<cdiv(KV * 96, 256), 256, 0, stream>>>(hyp_v, trs_v, bcv, KV);
  k_concat_b<<<cdiv(KT * 96, 256), 256, 0, stream>>>(hyp_t, trs_t, bct, KT);
  k_gemm96<<<cdiv(NI, BM), 256, 0, stream>>>(feat_v, bcv, ihv, itfv, NI, KV);
  k_gemm96<<<cdiv(NI, BM), 256, 0, stream>>>(feat_t, bct, iht, itft, NI, KT);

  // ---- uh_logits = R @ ih_logits (before softmax!) ----
  k_spmm32<<<cdiv(NU * 32, 256), 256, 0, stream>>>(ptrR, colR, valR, ihv, uhv, NU);
  k_spmm32<<<cdiv(NU * 32, 256), 256, 0, stream>>>(ptrR, colR, valR, iht, uht, NU);

  // ---- gumbel softmax in place ----
  k_gumbel_softmax<<<cdiv(NI, 8), 256, 0, stream>>>(ihv, NI, ks[0][0], ks[0][1]);
  k_gumbel_softmax<<<cdiv(NU, 8), 256, 0, stream>>>(uhv, NU, ks[0][2], ks[0][3]);
  k_gumbel_softmax<<<cdiv(NI, 8), 256, 0, stream>>>(iht, NI, ks[1][0], ks[1][1]);
  k_gumbel_softmax<<<cdiv(NU, 8), 256, 0, stream>>>(uht, NU, ks[1][2], ks[1][3]);

  // ---- UI propagation: cge = (e0 + e1 + e2)/3 ----
  k_copy<<<cdiv(NU * 64, 256), 256, 0, stream>>>(Gu, ego, NU * 64);
  k_copy<<<cdiv(NI * 64, 256), 256, 0, stream>>>(Gi, ego + (size_t)NU * 64, NI * 64);
  k_spmm64<<<cdiv(NN * 64, 256), 256, 0, stream>>>(ptrA, colA, valA, ego, t1b, NN, nullptr);
  k_spmm64<<<cdiv(NN * 64, 256), 256, 0, stream>>>(ptrA, colA, valA, t1b, t2b, NN, nullptr);
  k_cge<<<cdiv(NN * 64, 256), 256, 0, stream>>>(ego, t1b, t2b, cgeb, NN * 64);

  // ---- modality graph embeddings (reuse ego as mge0, t1b as mge1) ----
  // v
  k_spmm64<<<cdiv(NU * 64, 256), 256, 0, stream>>>(ptrR, colR, valR, itfv, ego, NU, inv_inters);
  k_copy<<<cdiv(NI * 64, 256), 256, 0, stream>>>(itfv, ego + (size_t)NU * 64, NI * 64);
  k_spmm64<<<cdiv(NN * 64, 256), 256, 0, stream>>>(ptrA, colA, valA, ego, t1b, NN, nullptr);
  k_l2norm_add<<<cdiv(NN * 64, 256), 256, 0, stream>>>(t1b, msum, NN);
  // t
  k_spmm64<<<cdiv(NU * 64, 256), 256, 0, stream>>>(ptrR, colR, valR, itft, ego, NU, inv_inters);
  k_copy<<<cdiv(NI * 64, 256), 256, 0, stream>>>(itft, ego + (size_t)NU * 64, NI * 64);
  k_spmm64<<<cdiv(NN * 64, 256), 256, 0, stream>>>(ptrA, colA, valA, ego, t1b, NN, nullptr);
  k_l2norm_add<<<cdiv(NN * 64, 256), 256, 0, stream>>>(t1b, msum, NN);

  // ---- hypergraph pass: lat = ih^T @ item_cge; u_ret = uh@lat; i_ret = ih@lat ----
  const float* item_cge = cgeb + (size_t)NU * 64;
  k_lat<<<cdiv(NI, 128), 256, 0, stream>>>(ihv, item_cge, latv, NI);
  k_hyper_out<<<cdiv(NU, 4), 256, 0, stream>>>(uhv, latv, o2, NU);
  k_hyper_out<<<cdiv(NI, 4), 256, 0, stream>>>(ihv, latv, o3, NI);
  k_lat<<<cdiv(NI, 128), 256, 0, stream>>>(iht, item_cge, latt, NI);
  k_hyper_out<<<cdiv(NU, 4), 256, 0, stream>>>(uht, latt, o4, NU);
  k_hyper_out<<<cdiv(NI, 4), 256, 0, stream>>>(iht, latt, o5, NI);

  // ---- final combine ----
  k_final<<<cdiv(NN * 64, 256), 256, 0, stream>>>(cgeb, msum, o2, o3, o4, o5, o0, o1);
}